// Round 2
// baseline (380.057 us; speedup 1.0000x reference)
//
#include <hip/hip_runtime.h>
#include <stdint.h>

#define T 16
#define NB 8
#define NROI 20000
#define NA 5
#define MM (NROI + NA)   // 20005
#define RPI 128
#define FGPI 32
#define SORTCAP 32768

// ---------------- threefry2x32 (JAX-exact, 20 rounds) ----------------
__device__ __forceinline__ void tf2x32(uint32_t k0, uint32_t k1,
                                       uint32_t x0, uint32_t x1,
                                       uint32_t& o0, uint32_t& o1) {
  uint32_t ks2 = k0 ^ k1 ^ 0x1BD11BDAu;
  x0 += k0; x1 += k1;
#define ROUND(r) { x0 += x1; x1 = (x1 << (r)) | (x1 >> (32 - (r))); x1 ^= x0; }
  ROUND(13) ROUND(15) ROUND(26) ROUND(6)
  x0 += k1; x1 += ks2 + 1u;
  ROUND(17) ROUND(29) ROUND(16) ROUND(24)
  x0 += ks2; x1 += k0 + 2u;
  ROUND(13) ROUND(15) ROUND(26) ROUND(6)
  x0 += k0; x1 += k1 + 3u;
  ROUND(17) ROUND(29) ROUND(16) ROUND(24)
  x0 += k1; x1 += ks2 + 4u;
  ROUND(13) ROUND(15) ROUND(26) ROUND(6)
  x0 += ks2; x1 += k0 + 5u;
#undef ROUND
  o0 = x0; o1 = x1;
}

__device__ __forceinline__ uint32_t rbits32(uint32_t k0, uint32_t k1, uint32_t i) {
  uint32_t a, b; tf2x32(k0, k1, 0u, i, a, b); return a ^ b;
}
__device__ __forceinline__ float uni01(uint32_t bits) {
  return __uint_as_float((bits >> 9) | 0x3f800000u) - 1.0f;
}

// ---------------- kernel 1: tiny init (counts + per-image subkeys) ----------------
__global__ __launch_bounds__(64) void k_init(int* __restrict__ counts,
                                             uint32_t* __restrict__ keys) {
  int tid = threadIdx.x;
  if (tid < NB * 4) counts[tid] = ((tid & 3) >= 2) ? MM : 0;  // [fg_num, bg_num, min_nonfg, min_nonbg]
  if (tid < NB) {
    uint32_t r0, r1; tf2x32(0u, 42u, 0u, (uint32_t)tid, r0, r1);
    for (int j = 0; j < 4; ++j) {
      uint32_t a, b; tf2x32(r0, r1, 0u, (uint32_t)j, a, b);
      keys[(tid * 4 + j) * 2 + 0] = a;
      keys[(tid * 4 + j) * 2 + 1] = b;
    }
  }
}

// ---------------- kernel 2: 8 lanes/roi (one per anchor), classify, append ----------------
__global__ __launch_bounds__(256) void k_overlap(const float* __restrict__ tubes,
                                                 const float* __restrict__ gtb,
                                                 unsigned char* __restrict__ asg,
                                                 uint64_t* __restrict__ fgk,
                                                 uint64_t* __restrict__ bgk,
                                                 int* __restrict__ counts,
                                                 const uint32_t* __restrict__ keys) {
  int img = blockIdx.y;
  __shared__ float4 g2[T][8];     // [t][anchor] box, anchors 5..7 = zero box
  __shared__ float gar2[T][8];
  for (int i = threadIdx.x; i < T * 8; i += 256) {
    int t = i >> 3, a = i & 7;
    float4 v = make_float4(0.f, 0.f, 0.f, 0.f); float ar = 1.0f;
    if (a < NA) {
      const float* p = gtb + (((size_t)img * NA + a) * T + t) * 5;
      v = make_float4(p[0], p[1], p[2], p[3]);
      ar = (v.z - v.x + 1.0f) * (v.w - v.y + 1.0f);
    }
    g2[t][a] = v; gar2[t][a] = ar;
  }
  __syncthreads();

  int n = blockIdx.x * 32 + (threadIdx.x >> 3);
  bool valid = n < MM;
  int nn = valid ? n : MM - 1;
  int lane = threadIdx.x & 63;
  int la = threadIdx.x & 7;       // anchor this lane evaluates (5..7 = junk, discarded)

  float s = 0.0f;
  if (nn < NROI) {
    const float* p = tubes + ((size_t)img * NROI + nn) * 7;
    float rx1 = p[1], ry1 = p[2], rx2 = p[4], ry2 = p[5];
    int sf = (int)rintf(p[3]), ef = (int)rintf(p[6]);
    float rar = (rx2 - rx1 + 1.0f) * (ry2 - ry1 + 1.0f);
#pragma unroll
    for (int t = 0; t < T; ++t) {
      float4 gg = g2[t][la]; float ag = gar2[t][la];
      float iw = fmaxf(fminf(rx2, gg.z) - fmaxf(rx1, gg.x) + 1.0f, 0.0f);
      float ih = fmaxf(fminf(ry2, gg.w) - fmaxf(ry1, gg.y) + 1.0f, 0.0f);
      float inter = iw * ih;
      float q = inter / (rar + ag - inter);
      s += ((t >= sf) && (t <= ef)) ? q : 0.0f;   // +0.0 terms preserve exact sum
    }
  } else {
    int ga = nn - NROI;
#pragma unroll
    for (int t = 0; t < T; ++t) {
      float4 e = g2[t][ga]; float ar = gar2[t][ga];
      float4 gg = g2[t][la]; float ag = gar2[t][la];
      float iw = fmaxf(fminf(e.z, gg.z) - fmaxf(e.x, gg.x) + 1.0f, 0.0f);
      float ih = fmaxf(fminf(e.w, gg.w) - fmaxf(e.y, gg.y) + 1.0f, 0.0f);
      float inter = iw * ih;
      s += inter / (ar + ag - inter);
    }
  }
  float ov = s / 16.0f;

  // first-max argmax across anchors 0..4 (lanes base8+0..4)
  int base8 = lane & ~7;
  float o0 = __shfl(ov, base8 + 0);
  float o1 = __shfl(ov, base8 + 1);
  float o2 = __shfl(ov, base8 + 2);
  float o3 = __shfl(ov, base8 + 3);
  float o4 = __shfl(ov, base8 + 4);
  float best = o0; int barg = 0;
  if (o1 > best) { best = o1; barg = 1; }
  if (o2 > best) { best = o2; barg = 2; }
  if (o3 > best) { best = o3; barg = 3; }
  if (o4 > best) { best = o4; barg = 4; }

  bool lead = (la == 0) && valid;
  if (lead) asg[(size_t)img * MM + n] = (unsigned char)barg;

  int base = img * 4;
  bool isfg = best >= 0.5f;
  bool isbg = (best < 0.5f) && (best >= 0.1f);

  if (lead && isfg) {
    unsigned long long mk = __ballot(1);
    int ldr = __ffsll(mk) - 1;
    int c = __popcll(mk);
    int bp = 0;
    if (lane == ldr) bp = atomicAdd(&counts[base + 0], c);
    bp = __shfl(bp, ldr);
    int pos = bp + __popcll(mk & ((1ULL << lane) - 1ULL));
    uint32_t m = rbits32(keys[(base + 0) * 2], keys[(base + 0) * 2 + 1], (uint32_t)n) >> 9;
    fgk[(size_t)img * SORTCAP + pos] = ((uint64_t)m << 32) | (uint32_t)n;
  }
  if (lead && isbg) {
    unsigned long long mk = __ballot(1);
    int ldr = __ffsll(mk) - 1;
    int c = __popcll(mk);
    int bp = 0;
    if (lane == ldr) bp = atomicAdd(&counts[base + 1], c);
    bp = __shfl(bp, ldr);
    int pos = bp + __popcll(mk & ((1ULL << lane) - 1ULL));
    uint32_t m = rbits32(keys[(base + 1) * 2], keys[(base + 1) * 2 + 1], (uint32_t)n) >> 9;
    bgk[(size_t)img * SORTCAP + pos] = ((uint64_t)m << 32) | (uint32_t)n;
  }

  // wave-aggregated atomicMin of smallest non-member index
  int v1m = (lead && !isfg) ? n : 0x7FFFFFFF;
  int v2m = (lead && !isbg) ? n : 0x7FFFFFFF;
#pragma unroll
  for (int off = 32; off; off >>= 1) {
    v1m = min(v1m, __shfl_xor(v1m, off));
    v2m = min(v2m, __shfl_xor(v2m, off));
  }
  if (lane == 0) {
    if (v1m != 0x7FFFFFFF) atomicMin(&counts[base + 2], v1m);
    if (v2m != 0x7FFFFFFF) atomicMin(&counts[base + 3], v2m);
  }
}

// ---------------- kernel 3: per-list bitonic sort, LDS when n<=8192 ----------------
__global__ __launch_bounds__(1024) void k_sort(uint64_t* __restrict__ fgk,
                                               uint64_t* __restrict__ bgk,
                                               const int* __restrict__ counts) {
  __shared__ uint64_t buf[8192];   // 64 KiB
  int list = blockIdx.x;           // (img<<1)|which
  int img = list >> 1;
  uint64_t* arr = ((list & 1) ? bgk : fgk) + (size_t)img * SORTCAP;
  int cnt = counts[img * 4 + (list & 1)];
  if (cnt <= 1) return;
  int n = 2; while (n < cnt) n <<= 1;
  if (n <= 8192) {
    for (int i = threadIdx.x; i < n; i += 1024) buf[i] = (i < cnt) ? arr[i] : ~0ULL;
    __syncthreads();
    for (int k = 2; k <= n; k <<= 1) {
      for (int j = k >> 1; j; j >>= 1) {
        for (int i = threadIdx.x; i < n; i += 1024) {
          int ixj = i ^ j;
          if (ixj > i) {
            uint64_t a = buf[i], b = buf[ixj];
            bool up = (i & k) == 0;
            if (up ? (a > b) : (a < b)) { buf[i] = b; buf[ixj] = a; }
          }
        }
        __syncthreads();
      }
    }
    for (int i = threadIdx.x; i < cnt; i += 1024) arr[i] = buf[i];
  } else {
    for (int i = cnt + threadIdx.x; i < n; i += 1024) arr[i] = ~0ULL;
    __syncthreads();
    for (int k = 2; k <= n; k <<= 1) {
      for (int j = k >> 1; j; j >>= 1) {
        for (int i = threadIdx.x; i < n; i += 1024) {
          int ixj = i ^ j;
          if (ixj > i) {
            uint64_t a = arr[i], b = arr[ixj];
            bool up = (i & k) == 0;
            if (up ? (a > b) : (a < b)) { arr[i] = b; arr[ixj] = a; }
          }
        }
        __syncthreads();
      }
    }
  }
}

// ---------------- kernel 4: sampling logic -> keep indices + scalar outputs ----------------
__global__ __launch_bounds__(128) void k_keep(const float* __restrict__ tubes,
                                              const float* __restrict__ gtb,
                                              const float* __restrict__ gta,
                                              const unsigned char* __restrict__ asg,
                                              const uint64_t* __restrict__ fgk,
                                              const uint64_t* __restrict__ bgk,
                                              const int* __restrict__ counts,
                                              const uint32_t* __restrict__ keys,
                                              int* __restrict__ kp,
                                              float* __restrict__ out) {
  int img = blockIdx.x;
  int r = threadIdx.x;
  int base = img * 4;
  int fg_num = counts[base + 0], bg_num = counts[base + 1];
  int min_nonfg = counts[base + 2], min_nonbg = counts[base + 3];

  float u3 = uni01(rbits32(keys[(base + 2) * 2], keys[(base + 2) * 2 + 1], (uint32_t)r));
  float u4 = uni01(rbits32(keys[(base + 3) * 2], keys[(base + 3) * 2 + 1], (uint32_t)r));

  int fg_this = (bg_num > 0) ? min(FGPI, fg_num) : (fg_num > 0 ? RPI : 0);
  const uint64_t* fga = fgk + (size_t)img * SORTCAP;
  const uint64_t* bga = bgk + (size_t)img * SORTCAP;

  int fg_idx;
  if (bg_num > 0) {
    fg_idx = (int)(uint32_t)(fga[r] & 0xffffffffULL);
  } else {
    int q = (int)(u3 * (float)max(fg_num, 1));
    fg_idx = (q >= fg_num)
               ? ((fg_num >= MM) ? (int)(uint32_t)(fga[MM - 1] & 0xffffffffULL) : min_nonfg)
               : (int)(uint32_t)(fga[q] & 0xffffffffULL);
  }
  int qb = (int)(u4 * (float)max(bg_num, 1));
  int bg_idx = (qb >= bg_num)
                 ? ((bg_num >= MM) ? (int)(uint32_t)(bga[MM - 1] & 0xffffffffULL) : min_nonbg)
                 : (int)(uint32_t)(bga[qb] & 0xffffffffULL);

  bool is_fg = r < fg_this;
  int keep = is_fg ? fg_idx : bg_idx;
  int ak = asg[(size_t)img * MM + keep];
  float glab = gtb[(((size_t)img * NA + ak) * T + 0) * 5 + 4];
  float lab = is_fg ? glab : 0.0f;

  size_t row = (size_t)img * RPI + r;
  kp[row] = keep;

  float* o_rois = out;
  float* o_tub = out + (size_t)NB * RPI * 65;
  float* o_lab = o_tub + (size_t)NB * RPI * 7;
  float* pt = o_tub + row * 7;

  o_rois[row * 65] = (float)img;
  pt[0] = (float)img;
  if (keep < NROI) {
    const float* p = tubes + ((size_t)img * NROI + keep) * 7;
#pragma unroll
    for (int c = 1; c < 7; ++c) pt[c] = p[c];
  } else {
    const float* p = gta + ((size_t)img * NA + (keep - NROI)) * 7;
#pragma unroll
    for (int c = 1; c < 7; ++c) pt[c] = p[c - 1];
  }
  o_lab[row] = lab;
}

// ---------------- kernel 5: per-(row,frame) output writer ----------------
__global__ __launch_bounds__(256) void k_write(const float* __restrict__ tubes,
                                               const float* __restrict__ gtb,
                                               const unsigned char* __restrict__ asg,
                                               const int* __restrict__ kp,
                                               float* __restrict__ out) {
  int tid = blockIdx.x * 256 + threadIdx.x;   // 8*128*16 = 16384 threads
  int row = tid >> 4;
  int t = tid & 15;
  int img = row >> 7;
  int keep = kp[row];
  int ak = asg[(size_t)img * MM + keep];

  float* o_rois = out;
  float* o_lab = out + (size_t)NB * RPI * 65 + (size_t)NB * RPI * 7;
  float* o_tgt = o_lab + (size_t)NB * RPI;
  float* o_in  = o_tgt + (size_t)NB * RPI * 64;
  float* o_ou  = o_in  + (size_t)NB * RPI * 64;

  float lab = o_lab[row];
  bool pos = lab > 0.0f;
  float posf = pos ? 1.0f : 0.0f;

  float ex1, ey1, ex2, ey2;
  if (keep < NROI) {
    const float* p = tubes + ((size_t)img * NROI + keep) * 7;
    int sf = (int)rintf(p[3]), ef = (int)rintf(p[6]);
    bool in = (t >= sf) && (t <= ef);
    ex1 = in ? p[1] : 0.0f; ey1 = in ? p[2] : 0.0f;
    ex2 = in ? p[4] : 0.0f; ey2 = in ? p[5] : 0.0f;
  } else {
    const float* p = gtb + (((size_t)img * NA + (keep - NROI)) * T + t) * 5;
    ex1 = p[0]; ey1 = p[1]; ex2 = p[2]; ey2 = p[3];
  }

  float* pr = o_rois + (size_t)row * 65 + 1 + 4 * t;
  pr[0] = ex1; pr[1] = ey1; pr[2] = ex2; pr[3] = ey2;

  const float* gp = gtb + (((size_t)img * NA + ak) * T + t) * 5;
  float gx1 = gp[0], gy1 = gp[1], gx2 = gp[2], gy2 = gp[3];
  float ew = ex2 - ex1 + 1.0f, eh = ey2 - ey1 + 1.0f;
  float ecx = ex1 + 0.5f * ew, ecy = ey1 + 0.5f * eh;
  float gw = gx2 - gx1 + 1.0f, gh = gy2 - gy1 + 1.0f;
  float gcx = gx1 + 0.5f * gw, gcy = gy1 + 0.5f * gh;
  float t0 = ((gcx - ecx) / ew) / 0.1f;
  float t1 = ((gcy - ecy) / eh) / 0.1f;
  float t2 = logf(gw / ew) / 0.2f;
  float t3 = logf(gh / eh) / 0.2f;

  *(float4*)(o_tgt + (size_t)row * 64 + 4 * t) =
      make_float4(pos ? t0 : 0.0f, pos ? t1 : 0.0f, pos ? t2 : 0.0f, pos ? t3 : 0.0f);
  float4 pf4 = make_float4(posf, posf, posf, posf);
  *(float4*)(o_in + (size_t)row * 64 + 4 * t) = pf4;
  *(float4*)(o_ou + (size_t)row * 64 + 4 * t) = pf4;
}

extern "C" void kernel_launch(void* const* d_in, const int* in_sizes, int n_in,
                              void* d_out, int out_size, void* d_ws, size_t ws_size,
                              hipStream_t stream) {
  const float* tubes = (const float*)d_in[0];       // [8][20000][7]
  const float* gtb   = (const float*)d_in[1];       // [8][5][16][5]
  const float* gta   = (const float*)d_in[2];       // [8][5][7]
  float* out = (float*)d_out;
  char* ws = (char*)d_ws;

  // workspace layout
  int*      counts = (int*)ws;                        // 32 ints @0
  uint32_t* keys   = (uint32_t*)(ws + 128);           // 64 u32 @128..384
  unsigned char* asg = (unsigned char*)(ws + 384);    // 160040 B -> ends 160424
  int* kp = (int*)(ws + 160424);                      // 1024 ints -> ends 164520
  uint64_t* fgk = (uint64_t*)(ws + 164520);           // 8-aligned (164520 % 8 == 0)
  uint64_t* bgk = fgk + (size_t)NB * SORTCAP;
  // total = 164520 + 2*8*32768*8 = 4,358,824 bytes

  k_init<<<1, 64, 0, stream>>>(counts, keys);
  dim3 gA((MM + 31) / 32, NB);
  k_overlap<<<gA, 256, 0, stream>>>(tubes, gtb, asg, fgk, bgk, counts, keys);
  k_sort<<<16, 1024, 0, stream>>>(fgk, bgk, counts);
  k_keep<<<NB, RPI, 0, stream>>>(tubes, gtb, gta, asg, fgk, bgk, counts, keys, kp, out);
  k_write<<<64, 256, 0, stream>>>(tubes, gtb, asg, kp, out);
}

// Round 3
// 86.079 us; speedup vs baseline: 4.4152x; 4.4152x over previous
//
#include <hip/hip_runtime.h>
#include <stdint.h>

#define T 16
#define NB 8
#define NROI 20000
#define NA 5
#define MM (NROI + NA)   // 20005
#define RPI 128
#define FGPI 32
#define SORTCAP 32768

// ---------------- threefry2x32 (JAX-exact, 20 rounds) ----------------
__device__ __forceinline__ void tf2x32(uint32_t k0, uint32_t k1,
                                       uint32_t x0, uint32_t x1,
                                       uint32_t& o0, uint32_t& o1) {
  uint32_t ks2 = k0 ^ k1 ^ 0x1BD11BDAu;
  x0 += k0; x1 += k1;
#define ROUND(r) { x0 += x1; x1 = (x1 << (r)) | (x1 >> (32 - (r))); x1 ^= x0; }
  ROUND(13) ROUND(15) ROUND(26) ROUND(6)
  x0 += k1; x1 += ks2 + 1u;
  ROUND(17) ROUND(29) ROUND(16) ROUND(24)
  x0 += ks2; x1 += k0 + 2u;
  ROUND(13) ROUND(15) ROUND(26) ROUND(6)
  x0 += k0; x1 += k1 + 3u;
  ROUND(17) ROUND(29) ROUND(16) ROUND(24)
  x0 += k1; x1 += ks2 + 4u;
  ROUND(13) ROUND(15) ROUND(26) ROUND(6)
  x0 += ks2; x1 += k0 + 5u;
#undef ROUND
  o0 = x0; o1 = x1;
}

__device__ __forceinline__ uint32_t rbits32(uint32_t k0, uint32_t k1, uint32_t i) {
  uint32_t a, b; tf2x32(k0, k1, 0u, i, a, b); return a ^ b;
}
__device__ __forceinline__ float uni01(uint32_t bits) {
  return __uint_as_float((bits >> 9) | 0x3f800000u) - 1.0f;
}

// ---------------- kernel 1: tiny init (counts + per-image subkeys) ----------------
__global__ __launch_bounds__(64) void k_init(int* __restrict__ counts,
                                             uint32_t* __restrict__ keys) {
  int tid = threadIdx.x;
  if (tid < NB * 4) counts[tid] = ((tid & 3) >= 2) ? MM : 0;  // [fg_num, bg_num, min_nonfg, min_nonbg]
  if (tid < NB) {
    uint32_t r0, r1; tf2x32(0u, 42u, 0u, (uint32_t)tid, r0, r1);
    for (int j = 0; j < 4; ++j) {
      uint32_t a, b; tf2x32(r0, r1, 0u, (uint32_t)j, a, b);
      keys[(tid * 4 + j) * 2 + 0] = a;
      keys[(tid * 4 + j) * 2 + 1] = b;
    }
  }
}

// ---------------- kernel 2: 1 thread/roi, unrolled 5x16 IoU, aggregated atomics ----------------
__global__ __launch_bounds__(256) void k_overlap(const float* __restrict__ tubes,
                                                 const float* __restrict__ gtb,
                                                 unsigned char* __restrict__ asg,
                                                 uint64_t* __restrict__ fgk,
                                                 uint64_t* __restrict__ bgk,
                                                 int* __restrict__ counts,
                                                 const uint32_t* __restrict__ keys) {
  int img = blockIdx.y;
  __shared__ float4 g4[NA][T];
  __shared__ float gar[NA][T];
  for (int i = threadIdx.x; i < NA * T; i += 256) {
    int a = i / T, t = i - a * T;
    const float* p = gtb + (((size_t)img * NA + a) * T + t) * 5;
    float4 v = make_float4(p[0], p[1], p[2], p[3]);
    g4[a][t] = v;
    gar[a][t] = (v.z - v.x + 1.0f) * (v.w - v.y + 1.0f);
  }
  __syncthreads();

  int n = blockIdx.x * 256 + threadIdx.x;
  bool valid = n < MM;
  int nn = valid ? n : MM - 1;
  int lane = threadIdx.x & 63;

  float best = -1.0f; int barg = 0;
  if (nn < NROI) {
    const float* p = tubes + ((size_t)img * NROI + nn) * 7;
    float rx1 = p[1], ry1 = p[2], rx2 = p[4], ry2 = p[5];
    int sf = (int)rintf(p[3]), ef = (int)rintf(p[6]);
    float rar = (rx2 - rx1 + 1.0f) * (ry2 - ry1 + 1.0f);
#pragma unroll
    for (int a = 0; a < NA; ++a) {
      float s = 0.0f;
#pragma unroll
      for (int t = 0; t < T; ++t) {
        float4 gg = g4[a][t]; float ag = gar[a][t];
        float iw = fmaxf(fminf(rx2, gg.z) - fmaxf(rx1, gg.x) + 1.0f, 0.0f);
        float ih = fmaxf(fminf(ry2, gg.w) - fmaxf(ry1, gg.y) + 1.0f, 0.0f);
        float inter = iw * ih;
        float q = inter / (rar + ag - inter);
        s += ((t >= sf) && (t <= ef)) ? q : 0.0f;   // +0.0 keeps exact sum (verified r2)
      }
      float ov = s / 16.0f;
      if (ov > best) { best = ov; barg = a; }       // first-max == jnp.argmax
    }
  } else {
    int ga = nn - NROI;
#pragma unroll
    for (int a = 0; a < NA; ++a) {
      float s = 0.0f;
#pragma unroll
      for (int t = 0; t < T; ++t) {
        float4 e = g4[ga][t]; float ar = gar[ga][t];
        float4 gg = g4[a][t]; float ag = gar[a][t];
        float iw = fmaxf(fminf(e.z, gg.z) - fmaxf(e.x, gg.x) + 1.0f, 0.0f);
        float ih = fmaxf(fminf(e.w, gg.w) - fmaxf(e.y, gg.y) + 1.0f, 0.0f);
        float inter = iw * ih;
        s += inter / (ar + ag - inter);
      }
      float ov = s / 16.0f;
      if (ov > best) { best = ov; barg = a; }
    }
  }

  if (valid) asg[(size_t)img * MM + n] = (unsigned char)barg;

  int base = img * 4;
  bool isfg = valid && (best >= 0.5f);
  bool isbg = valid && (best < 0.5f) && (best >= 0.1f);

  if (isfg) {
    unsigned long long mk = __ballot(1);
    int ldr = __ffsll(mk) - 1;
    int bp = 0;
    if (lane == ldr) bp = atomicAdd(&counts[base + 0], __popcll(mk));
    bp = __shfl(bp, ldr);
    int pos = bp + __popcll(mk & ((1ULL << lane) - 1ULL));
    uint32_t m = rbits32(keys[(base + 0) * 2], keys[(base + 0) * 2 + 1], (uint32_t)n) >> 9;
    fgk[(size_t)img * SORTCAP + pos] = ((uint64_t)m << 32) | (uint32_t)n;
  }
  if (isbg) {
    unsigned long long mk = __ballot(1);
    int ldr = __ffsll(mk) - 1;
    int bp = 0;
    if (lane == ldr) bp = atomicAdd(&counts[base + 1], __popcll(mk));
    bp = __shfl(bp, ldr);
    int pos = bp + __popcll(mk & ((1ULL << lane) - 1ULL));
    uint32_t m = rbits32(keys[(base + 1) * 2], keys[(base + 1) * 2 + 1], (uint32_t)n) >> 9;
    bgk[(size_t)img * SORTCAP + pos] = ((uint64_t)m << 32) | (uint32_t)n;
  }

  // wave-aggregated atomicMin of smallest non-member index (all 64 lanes active)
  int v1m = (valid && !isfg) ? n : 0x7FFFFFFF;
  int v2m = (valid && !isbg) ? n : 0x7FFFFFFF;
#pragma unroll
  for (int off = 32; off; off >>= 1) {
    v1m = min(v1m, __shfl_xor(v1m, off));
    v2m = min(v2m, __shfl_xor(v2m, off));
  }
  if (lane == 0) {
    if (v1m != 0x7FFFFFFF) atomicMin(&counts[base + 2], v1m);
    if (v2m != 0x7FFFFFFF) atomicMin(&counts[base + 3], v2m);
  }
}

// ---------------- kernel 3: per-list bitonic sort, LDS when n<=8192 ----------------
__global__ __launch_bounds__(1024) void k_sort(uint64_t* __restrict__ fgk,
                                               uint64_t* __restrict__ bgk,
                                               const int* __restrict__ counts) {
  __shared__ uint64_t buf[8192];   // 64 KiB
  int list = blockIdx.x;           // (img<<1)|which
  int img = list >> 1;
  uint64_t* arr = ((list & 1) ? bgk : fgk) + (size_t)img * SORTCAP;
  int cnt = counts[img * 4 + (list & 1)];
  if (cnt <= 1) return;
  int n = 2; while (n < cnt) n <<= 1;
  if (n <= 8192) {
    for (int i = threadIdx.x; i < n; i += 1024) buf[i] = (i < cnt) ? arr[i] : ~0ULL;
    __syncthreads();
    for (int k = 2; k <= n; k <<= 1) {
      for (int j = k >> 1; j; j >>= 1) {
        for (int i = threadIdx.x; i < n; i += 1024) {
          int ixj = i ^ j;
          if (ixj > i) {
            uint64_t a = buf[i], b = buf[ixj];
            bool up = (i & k) == 0;
            if (up ? (a > b) : (a < b)) { buf[i] = b; buf[ixj] = a; }
          }
        }
        __syncthreads();
      }
    }
    for (int i = threadIdx.x; i < cnt; i += 1024) arr[i] = buf[i];
  } else {
    for (int i = cnt + threadIdx.x; i < n; i += 1024) arr[i] = ~0ULL;
    __syncthreads();
    for (int k = 2; k <= n; k <<= 1) {
      for (int j = k >> 1; j; j >>= 1) {
        for (int i = threadIdx.x; i < n; i += 1024) {
          int ixj = i ^ j;
          if (ixj > i) {
            uint64_t a = arr[i], b = arr[ixj];
            bool up = (i & k) == 0;
            if (up ? (a > b) : (a < b)) { arr[i] = b; arr[ixj] = a; }
          }
        }
        __syncthreads();
      }
    }
  }
}

// ---------------- kernel 4: sampling logic -> keep indices + scalar outputs ----------------
__global__ __launch_bounds__(128) void k_keep(const float* __restrict__ tubes,
                                              const float* __restrict__ gtb,
                                              const float* __restrict__ gta,
                                              const unsigned char* __restrict__ asg,
                                              const uint64_t* __restrict__ fgk,
                                              const uint64_t* __restrict__ bgk,
                                              const int* __restrict__ counts,
                                              const uint32_t* __restrict__ keys,
                                              int* __restrict__ kp,
                                              float* __restrict__ out) {
  int img = blockIdx.x;
  int r = threadIdx.x;
  int base = img * 4;
  int fg_num = counts[base + 0], bg_num = counts[base + 1];
  int min_nonfg = counts[base + 2], min_nonbg = counts[base + 3];

  float u3 = uni01(rbits32(keys[(base + 2) * 2], keys[(base + 2) * 2 + 1], (uint32_t)r));
  float u4 = uni01(rbits32(keys[(base + 3) * 2], keys[(base + 3) * 2 + 1], (uint32_t)r));

  int fg_this = (bg_num > 0) ? min(FGPI, fg_num) : (fg_num > 0 ? RPI : 0);
  const uint64_t* fga = fgk + (size_t)img * SORTCAP;
  const uint64_t* bga = bgk + (size_t)img * SORTCAP;

  int fg_idx;
  if (bg_num > 0) {
    fg_idx = (int)(uint32_t)(fga[r] & 0xffffffffULL);
  } else {
    int q = (int)(u3 * (float)max(fg_num, 1));
    fg_idx = (q >= fg_num)
               ? ((fg_num >= MM) ? (int)(uint32_t)(fga[MM - 1] & 0xffffffffULL) : min_nonfg)
               : (int)(uint32_t)(fga[q] & 0xffffffffULL);
  }
  int qb = (int)(u4 * (float)max(bg_num, 1));
  int bg_idx = (qb >= bg_num)
                 ? ((bg_num >= MM) ? (int)(uint32_t)(bga[MM - 1] & 0xffffffffULL) : min_nonbg)
                 : (int)(uint32_t)(bga[qb] & 0xffffffffULL);

  bool is_fg = r < fg_this;
  int keep = is_fg ? fg_idx : bg_idx;
  int ak = asg[(size_t)img * MM + keep];
  float glab = gtb[(((size_t)img * NA + ak) * T + 0) * 5 + 4];
  float lab = is_fg ? glab : 0.0f;

  size_t row = (size_t)img * RPI + r;
  kp[row] = keep;

  float* o_rois = out;
  float* o_tub = out + (size_t)NB * RPI * 65;
  float* o_lab = o_tub + (size_t)NB * RPI * 7;
  float* pt = o_tub + row * 7;

  o_rois[row * 65] = (float)img;
  pt[0] = (float)img;
  if (keep < NROI) {
    const float* p = tubes + ((size_t)img * NROI + keep) * 7;
#pragma unroll
    for (int c = 1; c < 7; ++c) pt[c] = p[c];
  } else {
    const float* p = gta + ((size_t)img * NA + (keep - NROI)) * 7;
#pragma unroll
    for (int c = 1; c < 7; ++c) pt[c] = p[c - 1];
  }
  o_lab[row] = lab;
}

// ---------------- kernel 5: per-(row,frame) output writer ----------------
__global__ __launch_bounds__(256) void k_write(const float* __restrict__ tubes,
                                               const float* __restrict__ gtb,
                                               const unsigned char* __restrict__ asg,
                                               const int* __restrict__ kp,
                                               float* __restrict__ out) {
  int tid = blockIdx.x * 256 + threadIdx.x;   // 8*128*16 = 16384 threads
  int row = tid >> 4;
  int t = tid & 15;
  int img = row >> 7;
  int keep = kp[row];
  int ak = asg[(size_t)img * MM + keep];

  float* o_rois = out;
  float* o_lab = out + (size_t)NB * RPI * 65 + (size_t)NB * RPI * 7;
  float* o_tgt = o_lab + (size_t)NB * RPI;
  float* o_in  = o_tgt + (size_t)NB * RPI * 64;
  float* o_ou  = o_in  + (size_t)NB * RPI * 64;

  float lab = o_lab[row];
  bool pos = lab > 0.0f;
  float posf = pos ? 1.0f : 0.0f;

  float ex1, ey1, ex2, ey2;
  if (keep < NROI) {
    const float* p = tubes + ((size_t)img * NROI + keep) * 7;
    int sf = (int)rintf(p[3]), ef = (int)rintf(p[6]);
    bool in = (t >= sf) && (t <= ef);
    ex1 = in ? p[1] : 0.0f; ey1 = in ? p[2] : 0.0f;
    ex2 = in ? p[4] : 0.0f; ey2 = in ? p[5] : 0.0f;
  } else {
    const float* p = gtb + (((size_t)img * NA + (keep - NROI)) * T + t) * 5;
    ex1 = p[0]; ey1 = p[1]; ex2 = p[2]; ey2 = p[3];
  }

  float* pr = o_rois + (size_t)row * 65 + 1 + 4 * t;
  pr[0] = ex1; pr[1] = ey1; pr[2] = ex2; pr[3] = ey2;

  const float* gp = gtb + (((size_t)img * NA + ak) * T + t) * 5;
  float gx1 = gp[0], gy1 = gp[1], gx2 = gp[2], gy2 = gp[3];
  float ew = ex2 - ex1 + 1.0f, eh = ey2 - ey1 + 1.0f;
  float ecx = ex1 + 0.5f * ew, ecy = ey1 + 0.5f * eh;
  float gw = gx2 - gx1 + 1.0f, gh = gy2 - gy1 + 1.0f;
  float gcx = gx1 + 0.5f * gw, gcy = gy1 + 0.5f * gh;
  float t0 = ((gcx - ecx) / ew) / 0.1f;
  float t1 = ((gcy - ecy) / eh) / 0.1f;
  float t2 = logf(gw / ew) / 0.2f;
  float t3 = logf(gh / eh) / 0.2f;

  *(float4*)(o_tgt + (size_t)row * 64 + 4 * t) =
      make_float4(pos ? t0 : 0.0f, pos ? t1 : 0.0f, pos ? t2 : 0.0f, pos ? t3 : 0.0f);
  float4 pf4 = make_float4(posf, posf, posf, posf);
  *(float4*)(o_in + (size_t)row * 64 + 4 * t) = pf4;
  *(float4*)(o_ou + (size_t)row * 64 + 4 * t) = pf4;
}

extern "C" void kernel_launch(void* const* d_in, const int* in_sizes, int n_in,
                              void* d_out, int out_size, void* d_ws, size_t ws_size,
                              hipStream_t stream) {
  const float* tubes = (const float*)d_in[0];       // [8][20000][7]
  const float* gtb   = (const float*)d_in[1];       // [8][5][16][5]
  const float* gta   = (const float*)d_in[2];       // [8][5][7]
  float* out = (float*)d_out;
  char* ws = (char*)d_ws;

  // workspace layout
  int*      counts = (int*)ws;                        // 32 ints @0
  uint32_t* keys   = (uint32_t*)(ws + 128);           // 64 u32 @128..384
  unsigned char* asg = (unsigned char*)(ws + 384);    // 160040 B -> ends 160424
  int* kp = (int*)(ws + 160424);                      // 1024 ints -> ends 164520
  uint64_t* fgk = (uint64_t*)(ws + 164520);           // 8-aligned (164520 % 8 == 0)
  uint64_t* bgk = fgk + (size_t)NB * SORTCAP;
  // total = 164520 + 2*8*32768*8 = 4,358,824 bytes

  k_init<<<1, 64, 0, stream>>>(counts, keys);
  dim3 gA((MM + 255) / 256, NB);
  k_overlap<<<gA, 256, 0, stream>>>(tubes, gtb, asg, fgk, bgk, counts, keys);
  k_sort<<<16, 1024, 0, stream>>>(fgk, bgk, counts);
  k_keep<<<NB, RPI, 0, stream>>>(tubes, gtb, gta, asg, fgk, bgk, counts, keys, kp, out);
  k_write<<<64, 256, 0, stream>>>(tubes, gtb, asg, kp, out);
}

// Round 4
// 54.120 us; speedup vs baseline: 7.0225x; 1.5905x over previous
//
#include <hip/hip_runtime.h>
#include <stdint.h>

#define T 16
#define NB 8
#define NROI 20000
#define NA 5
#define MM (NROI + NA)   // 20005
#define RPI 128
#define FGPI 32
#define SORTCAP 32768
#define CSTRIDE 32       // ints per image in counts (128B line padding)

// ---------------- threefry2x32 (JAX-exact, 20 rounds), host+device ----------------
__host__ __device__ __forceinline__ void tf2x32(uint32_t k0, uint32_t k1,
                                                uint32_t x0, uint32_t x1,
                                                uint32_t& o0, uint32_t& o1) {
  uint32_t ks2 = k0 ^ k1 ^ 0x1BD11BDAu;
  x0 += k0; x1 += k1;
#define ROUND(r) { x0 += x1; x1 = (x1 << (r)) | (x1 >> (32 - (r))); x1 ^= x0; }
  ROUND(13) ROUND(15) ROUND(26) ROUND(6)
  x0 += k1; x1 += ks2 + 1u;
  ROUND(17) ROUND(29) ROUND(16) ROUND(24)
  x0 += ks2; x1 += k0 + 2u;
  ROUND(13) ROUND(15) ROUND(26) ROUND(6)
  x0 += k0; x1 += k1 + 3u;
  ROUND(17) ROUND(29) ROUND(16) ROUND(24)
  x0 += k1; x1 += ks2 + 4u;
  ROUND(13) ROUND(15) ROUND(26) ROUND(6)
  x0 += ks2; x1 += k0 + 5u;
#undef ROUND
  o0 = x0; o1 = x1;
}

__device__ __forceinline__ uint32_t rbits32(uint32_t k0, uint32_t k1, uint32_t i) {
  uint32_t a, b; tf2x32(k0, k1, 0u, i, a, b); return a ^ b;
}
__device__ __forceinline__ float uni01(uint32_t bits) {
  return __uint_as_float((bits >> 9) | 0x3f800000u) - 1.0f;
}

struct Keys { uint32_t k[NB][4][2]; };   // host-precomputed subkeys, by-value kernarg

// ---------------- kernel 1: overlap + classify + block-aggregated append ----------------
__global__ __launch_bounds__(256) void k_overlap(const float* __restrict__ tubes,
                                                 const float* __restrict__ gtb,
                                                 unsigned char* __restrict__ asg,
                                                 uint64_t* __restrict__ fgk,
                                                 uint64_t* __restrict__ bgk,
                                                 int* __restrict__ counts,
                                                 Keys keys) {
  int img = blockIdx.y;
  int n = blockIdx.x * 256 + threadIdx.x;
  bool valid = n < MM;
  int nn = valid ? n : MM - 1;
  int lane = threadIdx.x & 63;
  int w = threadIdx.x >> 6;

  // prefetch tube row (latency hides under staging + barrier)
  float rx1 = 0.f, ry1 = 0.f, rx2 = 0.f, ry2 = 0.f, rsf = 0.f, ref_ = 0.f;
  bool isroi = nn < NROI;
  if (isroi) {
    const float* p = tubes + ((size_t)img * NROI + nn) * 7;
    rx1 = p[1]; ry1 = p[2]; rsf = p[3]; rx2 = p[4]; ry2 = p[5]; ref_ = p[6];
  }

  __shared__ float4 g4[NA][T];
  __shared__ float gar[NA][T];
  __shared__ int wagg[4][4];     // per wave: fgcnt, bgcnt, min_nonfg, min_nonbg
  __shared__ int bbase[2];
  for (int i = threadIdx.x; i < NA * T; i += 256) {
    int a = i / T, t = i - a * T;
    const float* p = gtb + (((size_t)img * NA + a) * T + t) * 5;
    float4 v = make_float4(p[0], p[1], p[2], p[3]);
    g4[a][t] = v;
    gar[a][t] = (v.z - v.x + 1.0f) * (v.w - v.y + 1.0f);
  }
  __syncthreads();

  float best = -1.0f; int barg = 0;
  if (isroi) {
    int sf = (int)rintf(rsf), ef = (int)rintf(ref_);
    float rar = (rx2 - rx1 + 1.0f) * (ry2 - ry1 + 1.0f);
#pragma unroll
    for (int a = 0; a < NA; ++a) {
      float s = 0.0f;
#pragma unroll
      for (int t = 0; t < T; ++t) {
        float4 gg = g4[a][t]; float ag = gar[a][t];
        float iw = fmaxf(fminf(rx2, gg.z) - fmaxf(rx1, gg.x) + 1.0f, 0.0f);
        float ih = fmaxf(fminf(ry2, gg.w) - fmaxf(ry1, gg.y) + 1.0f, 0.0f);
        float inter = iw * ih;
        float q = inter / (rar + ag - inter);
        s += ((t >= sf) && (t <= ef)) ? q : 0.0f;   // +0.0 keeps exact sum (verified r2/r3)
      }
      float ov = s / 16.0f;
      if (ov > best) { best = ov; barg = a; }       // first-max == jnp.argmax
    }
  } else {
    int ga = nn - NROI;
#pragma unroll
    for (int a = 0; a < NA; ++a) {
      float s = 0.0f;
#pragma unroll
      for (int t = 0; t < T; ++t) {
        float4 e = g4[ga][t]; float ar = gar[ga][t];
        float4 gg = g4[a][t]; float ag = gar[a][t];
        float iw = fmaxf(fminf(e.z, gg.z) - fmaxf(e.x, gg.x) + 1.0f, 0.0f);
        float ih = fmaxf(fminf(e.w, gg.w) - fmaxf(e.y, gg.y) + 1.0f, 0.0f);
        float inter = iw * ih;
        s += inter / (ar + ag - inter);
      }
      float ov = s / 16.0f;
      if (ov > best) { best = ov; barg = a; }
    }
  }

  if (valid) asg[(size_t)img * MM + n] = (unsigned char)barg;

  bool isfg = valid && (best >= 0.5f);
  bool isbg = valid && (best < 0.5f) && (best >= 0.1f);

  // full-wave ballots (before any barrier) — kept in registers for the append phase
  unsigned long long mfg = __ballot(isfg);
  unsigned long long mbg = __ballot(isbg);
  unsigned long long mnf = __ballot(valid && !isfg);
  unsigned long long mnb = __ballot(valid && !isbg);
  int wavebase = blockIdx.x * 256 + w * 64;
  if (lane == 0) {
    wagg[w][0] = __popcll(mfg);
    wagg[w][1] = __popcll(mbg);
    wagg[w][2] = mnf ? (wavebase + __ffsll(mnf) - 1) : 0x7FFFFFFF;
    wagg[w][3] = mnb ? (wavebase + __ffsll(mnb) - 1) : 0x7FFFFFFF;
  }
  __syncthreads();

  int cb = img * CSTRIDE;
  if (threadIdx.x == 0) {
    int tf_ = wagg[0][0] + wagg[1][0] + wagg[2][0] + wagg[3][0];
    int tb_ = wagg[0][1] + wagg[1][1] + wagg[2][1] + wagg[3][1];
    if (tf_) bbase[0] = atomicAdd(&counts[cb + 0], tf_);
    if (tb_) bbase[1] = atomicAdd(&counts[cb + 1], tb_);
    int mn = min(min(wagg[0][2], wagg[1][2]), min(wagg[2][2], wagg[3][2]));
    int mb = min(min(wagg[0][3], wagg[1][3]), min(wagg[2][3], wagg[3][3]));
    // counters init to 0; store MM-n so atomicMax tracks the min index
    if (mn != 0x7FFFFFFF) atomicMax(&counts[cb + 2], MM - mn);
    if (mb != 0x7FFFFFFF) atomicMax(&counts[cb + 3], MM - mb);
  }
  __syncthreads();

  unsigned long long below = (1ULL << lane) - 1ULL;
  if (isfg) {
    int prefix = 0;
#pragma unroll
    for (int w2 = 0; w2 < 4; ++w2) if (w2 < w) prefix += wagg[w2][0];
    int pos = bbase[0] + prefix + __popcll(mfg & below);
    uint32_t m = rbits32(keys.k[img][0][0], keys.k[img][0][1], (uint32_t)n) >> 9;
    fgk[(size_t)img * SORTCAP + pos] = ((uint64_t)m << 32) | (uint32_t)n;
  }
  if (isbg) {
    int prefix = 0;
#pragma unroll
    for (int w2 = 0; w2 < 4; ++w2) if (w2 < w) prefix += wagg[w2][1];
    int pos = bbase[1] + prefix + __popcll(mbg & below);
    uint32_t m = rbits32(keys.k[img][1][0], keys.k[img][1][1], (uint32_t)n) >> 9;
    bgk[(size_t)img * SORTCAP + pos] = ((uint64_t)m << 32) | (uint32_t)n;
  }
}

// ---------------- kernel 2: per-list bitonic sort, LDS when n<=8192 ----------------
__global__ __launch_bounds__(1024) void k_sort(uint64_t* __restrict__ fgk,
                                               uint64_t* __restrict__ bgk,
                                               const int* __restrict__ counts) {
  __shared__ uint64_t buf[8192];   // 64 KiB
  int list = blockIdx.x;           // (img<<1)|which
  int img = list >> 1;
  uint64_t* arr = ((list & 1) ? bgk : fgk) + (size_t)img * SORTCAP;
  int cnt = counts[img * CSTRIDE + (list & 1)];
  if (cnt <= 1) return;
  int n = 2; while (n < cnt) n <<= 1;
  if (n <= 8192) {
    for (int i = threadIdx.x; i < n; i += 1024) buf[i] = (i < cnt) ? arr[i] : ~0ULL;
    __syncthreads();
    for (int k = 2; k <= n; k <<= 1) {
      for (int j = k >> 1; j; j >>= 1) {
        for (int i = threadIdx.x; i < n; i += 1024) {
          int ixj = i ^ j;
          if (ixj > i) {
            uint64_t a = buf[i], b = buf[ixj];
            bool up = (i & k) == 0;
            if (up ? (a > b) : (a < b)) { buf[i] = b; buf[ixj] = a; }
          }
        }
        __syncthreads();
      }
    }
    for (int i = threadIdx.x; i < cnt; i += 1024) arr[i] = buf[i];
  } else {
    for (int i = cnt + threadIdx.x; i < n; i += 1024) arr[i] = ~0ULL;
    __syncthreads();
    for (int k = 2; k <= n; k <<= 1) {
      for (int j = k >> 1; j; j >>= 1) {
        for (int i = threadIdx.x; i < n; i += 1024) {
          int ixj = i ^ j;
          if (ixj > i) {
            uint64_t a = arr[i], b = arr[ixj];
            bool up = (i & k) == 0;
            if (up ? (a > b) : (a < b)) { arr[i] = b; arr[ixj] = a; }
          }
        }
        __syncthreads();
      }
    }
  }
}

// ---------------- kernel 3: fused sampling + all outputs (1 block / image) ----------------
__global__ __launch_bounds__(256) void k_sample(const float* __restrict__ tubes,
                                                const float* __restrict__ gtb,
                                                const float* __restrict__ gta,
                                                const unsigned char* __restrict__ asg,
                                                const uint64_t* __restrict__ fgk,
                                                const uint64_t* __restrict__ bgk,
                                                const int* __restrict__ counts,
                                                Keys keys,
                                                float* __restrict__ out) {
  int img = blockIdx.x;
  int tid = threadIdx.x;
  __shared__ int s_keep[RPI];
  __shared__ int s_ak[RPI];
  __shared__ float s_lab[RPI];

  float* o_rois = out;
  float* o_tub = out + (size_t)NB * RPI * 65;
  float* o_lab = o_tub + (size_t)NB * RPI * 7;
  float* o_tgt = o_lab + (size_t)NB * RPI;
  float* o_in  = o_tgt + (size_t)NB * RPI * 64;
  float* o_ou  = o_in  + (size_t)NB * RPI * 64;

  if (tid < RPI) {
    int r = tid;
    int cb = img * CSTRIDE;
    int fg_num = counts[cb + 0], bg_num = counts[cb + 1];
    int min_nonfg = MM - counts[cb + 2];   // slot==0 (never hit when used) -> MM
    int min_nonbg = MM - counts[cb + 3];

    float u3 = uni01(rbits32(keys.k[img][2][0], keys.k[img][2][1], (uint32_t)r));
    float u4 = uni01(rbits32(keys.k[img][3][0], keys.k[img][3][1], (uint32_t)r));

    int fg_this = (bg_num > 0) ? min(FGPI, fg_num) : (fg_num > 0 ? RPI : 0);
    const uint64_t* fga = fgk + (size_t)img * SORTCAP;
    const uint64_t* bga = bgk + (size_t)img * SORTCAP;

    int fg_idx;
    if (bg_num > 0) {
      fg_idx = (int)(uint32_t)(fga[r] & 0xffffffffULL);
    } else {
      int q = (int)(u3 * (float)max(fg_num, 1));
      fg_idx = (q >= fg_num)
                 ? ((fg_num >= MM) ? (int)(uint32_t)(fga[MM - 1] & 0xffffffffULL) : min_nonfg)
                 : (int)(uint32_t)(fga[q] & 0xffffffffULL);
    }
    int qb = (int)(u4 * (float)max(bg_num, 1));
    int bg_idx = (qb >= bg_num)
                   ? ((bg_num >= MM) ? (int)(uint32_t)(bga[MM - 1] & 0xffffffffULL) : min_nonbg)
                   : (int)(uint32_t)(bga[qb] & 0xffffffffULL);

    bool is_fg = r < fg_this;
    int keep = is_fg ? fg_idx : bg_idx;
    int ak = asg[(size_t)img * MM + keep];
    float glab = gtb[(((size_t)img * NA + ak) * T + 0) * 5 + 4];
    float lab = is_fg ? glab : 0.0f;

    s_keep[r] = keep; s_ak[r] = ak; s_lab[r] = lab;

    size_t row = (size_t)img * RPI + r;
    float* pt = o_tub + row * 7;
    o_rois[row * 65] = (float)img;
    pt[0] = (float)img;
    if (keep < NROI) {
      const float* p = tubes + ((size_t)img * NROI + keep) * 7;
#pragma unroll
      for (int c = 1; c < 7; ++c) pt[c] = p[c];
    } else {
      const float* p = gta + ((size_t)img * NA + (keep - NROI)) * 7;
#pragma unroll
      for (int c = 1; c < 7; ++c) pt[c] = p[c - 1];
    }
    o_lab[row] = lab;
  }
  __syncthreads();

  for (int i = tid; i < RPI * T; i += 256) {
    int rl = i >> 4;
    int t = i & 15;
    size_t row = (size_t)img * RPI + rl;
    int keep = s_keep[rl];
    int ak = s_ak[rl];
    float lab = s_lab[rl];
    bool pos = lab > 0.0f;
    float posf = pos ? 1.0f : 0.0f;

    float ex1, ey1, ex2, ey2;
    if (keep < NROI) {
      const float* p = tubes + ((size_t)img * NROI + keep) * 7;
      int sf = (int)rintf(p[3]), ef = (int)rintf(p[6]);
      bool in = (t >= sf) && (t <= ef);
      ex1 = in ? p[1] : 0.0f; ey1 = in ? p[2] : 0.0f;
      ex2 = in ? p[4] : 0.0f; ey2 = in ? p[5] : 0.0f;
    } else {
      const float* p = gtb + (((size_t)img * NA + (keep - NROI)) * T + t) * 5;
      ex1 = p[0]; ey1 = p[1]; ex2 = p[2]; ey2 = p[3];
    }

    float* pr = o_rois + row * 65 + 1 + 4 * t;
    pr[0] = ex1; pr[1] = ey1; pr[2] = ex2; pr[3] = ey2;

    const float* gp = gtb + (((size_t)img * NA + ak) * T + t) * 5;
    float gx1 = gp[0], gy1 = gp[1], gx2 = gp[2], gy2 = gp[3];
    float ew = ex2 - ex1 + 1.0f, eh = ey2 - ey1 + 1.0f;
    float ecx = ex1 + 0.5f * ew, ecy = ey1 + 0.5f * eh;
    float gw = gx2 - gx1 + 1.0f, gh = gy2 - gy1 + 1.0f;
    float gcx = gx1 + 0.5f * gw, gcy = gy1 + 0.5f * gh;
    float t0 = ((gcx - ecx) / ew) / 0.1f;
    float t1 = ((gcy - ecy) / eh) / 0.1f;
    float t2 = logf(gw / ew) / 0.2f;
    float t3 = logf(gh / eh) / 0.2f;

    *(float4*)(o_tgt + row * 64 + 4 * t) =
        make_float4(pos ? t0 : 0.0f, pos ? t1 : 0.0f, pos ? t2 : 0.0f, pos ? t3 : 0.0f);
    float4 pf4 = make_float4(posf, posf, posf, posf);
    *(float4*)(o_in + row * 64 + 4 * t) = pf4;
    *(float4*)(o_ou + row * 64 + 4 * t) = pf4;
  }
}

extern "C" void kernel_launch(void* const* d_in, const int* in_sizes, int n_in,
                              void* d_out, int out_size, void* d_ws, size_t ws_size,
                              hipStream_t stream) {
  const float* tubes = (const float*)d_in[0];       // [8][20000][7]
  const float* gtb   = (const float*)d_in[1];       // [8][5][16][5]
  const float* gta   = (const float*)d_in[2];       // [8][5][7]
  float* out = (float*)d_out;
  char* ws = (char*)d_ws;

  // host-side key derivation (pure, deterministic): key(42)=(0,42); foldlike splits
  Keys keys;
  for (int img = 0; img < NB; ++img) {
    uint32_t r0, r1; tf2x32(0u, 42u, 0u, (uint32_t)img, r0, r1);
    for (int j = 0; j < 4; ++j) {
      uint32_t a, b; tf2x32(r0, r1, 0u, (uint32_t)j, a, b);
      keys.k[img][j][0] = a; keys.k[img][j][1] = b;
    }
  }

  // workspace layout (counts padded: 32 ints = 128B per image)
  int* counts = (int*)ws;                             // 8*128 = 1024 B
  unsigned char* asg = (unsigned char*)(ws + 1024);   // 160040 B -> ends 161064
  uint64_t* fgk = (uint64_t*)(ws + 161064);           // 161064 % 8 == 0
  uint64_t* bgk = fgk + (size_t)NB * SORTCAP;
  // total = 161064 + 2*8*32768*8 = 4,355,368 bytes

  hipMemsetAsync(counts, 0, NB * CSTRIDE * sizeof(int), stream);
  dim3 gA((MM + 255) / 256, NB);
  k_overlap<<<gA, 256, 0, stream>>>(tubes, gtb, asg, fgk, bgk, counts, keys);
  k_sort<<<16, 1024, 0, stream>>>(fgk, bgk, counts);
  k_sample<<<NB, 256, 0, stream>>>(tubes, gtb, gta, asg, fgk, bgk, counts, keys, out);
}